// Round 3
// baseline (1373.175 us; speedup 1.0000x reference)
//
#include <hip/hip_runtime.h>
#include <math.h>

#define TPB 256
#define E 16           // elements per block
#define VSTR 264       // [e][k] stride for vector-activation LDS (f16)
#define SSTR 392       // scat stride
#define SLOPE_VN 0.2f
#define SLOPE_SCA 0.01f
#define EPS_VN 1e-6f

using hfrag = __attribute__((ext_vector_type(8))) _Float16;
using h4    = __attribute__((ext_vector_type(4))) _Float16;
using ffrag = __attribute__((ext_vector_type(4))) float;

__device__ __forceinline__ ffrag mfma(hfrag a, hfrag b, ffrag c) {
  return __builtin_amdgcn_mfma_f32_16x16x32_f16(a, b, c, 0, 0, 0);
}

// ---------------- pre-pass kernels ----------------
struct CvtJobs { const float* src[12]; _Float16* dst[12]; int n[12]; };

__global__ void cvt_kernel(CvtJobs J) {
  const int j = blockIdx.y;
  const float* __restrict__ s = J.src[j];
  _Float16* __restrict__ d = J.dst[j];
  const int n = J.n[j];
  for (int i = blockIdx.x * blockDim.x + threadIdx.x; i < n;
       i += gridDim.x * blockDim.x)
    d[i] = (_Float16)s[i];
}

// out[o][c] = sum_h A[o*H+h] * B[h*C+c]   (f32 in, f16 out)
struct FuseJobs { const float* A[8]; const float* B[8]; _Float16* out[8]; int O[8], H[8], C[8]; };

__global__ void fuse_kernel(FuseJobs J) {
  const int j = blockIdx.y;
  const int o = blockIdx.x;
  if (o >= J.O[j]) return;
  const float* __restrict__ A = J.A[j] + (size_t)o * J.H[j];
  const float* __restrict__ B = J.B[j];
  _Float16* __restrict__ out = J.out[j] + (size_t)o * J.C[j];
  const int H = J.H[j], C = J.C[j];
  for (int c = threadIdx.x; c < C; c += blockDim.x) {
    float acc = 0.f;
    for (int h = 0; h < H; ++h) acc += A[h] * B[(size_t)h * C + c];
    out[c] = (_Float16)acc;
  }
}

// ---------------- GEMM helpers ----------------
// Dual vector GEMM sharing B: accA += Wa*v, accB += Wb*v  (K = KS*32)
template<int TT, int KS>
__device__ __forceinline__ void gemmV2(const _Float16* __restrict__ Wa,
                                       const _Float16* __restrict__ Wb,
                                       const _Float16* vb,
                                       ffrag (&accA)[TT][3], ffrag (&accB)[TT][3]) {
  const int C = KS * 32;
  const int m = threadIdx.x & 15;
  const int q = (threadIdx.x >> 4) & 3;
  const int w = threadIdx.x >> 6;
  #pragma unroll
  for (int ks = 0; ks < KS; ++ks) {
    const int k = ks * 32 + q * 8;
    hfrag b0 = *(const hfrag*)(vb + 0 * E * VSTR + m * VSTR + k);
    hfrag b1 = *(const hfrag*)(vb + 1 * E * VSTR + m * VSTR + k);
    hfrag b2 = *(const hfrag*)(vb + 2 * E * VSTR + m * VSTR + k);
    #pragma unroll
    for (int t = 0; t < TT; ++t) {
      const int row = (w + t * 4) * 16 + m;
      hfrag a1 = *(const hfrag*)(Wa + (size_t)row * C + k);
      hfrag a2 = *(const hfrag*)(Wb + (size_t)row * C + k);
      accA[t][0] = mfma(a1, b0, accA[t][0]);
      accA[t][1] = mfma(a1, b1, accA[t][1]);
      accA[t][2] = mfma(a1, b2, accA[t][2]);
      accB[t][0] = mfma(a2, b0, accB[t][0]);
      accB[t][1] = mfma(a2, b1, accB[t][1]);
      accB[t][2] = mfma(a2, b2, accB[t][2]);
    }
  }
}

// Single vector GEMM
template<int TT, int KS>
__device__ __forceinline__ void gemmV(const _Float16* __restrict__ W,
                                      const _Float16* vb, ffrag (&acc)[TT][3]) {
  const int C = KS * 32;
  const int m = threadIdx.x & 15;
  const int q = (threadIdx.x >> 4) & 3;
  const int w = threadIdx.x >> 6;
  #pragma unroll
  for (int ks = 0; ks < KS; ++ks) {
    const int k = ks * 32 + q * 8;
    hfrag b0 = *(const hfrag*)(vb + 0 * E * VSTR + m * VSTR + k);
    hfrag b1 = *(const hfrag*)(vb + 1 * E * VSTR + m * VSTR + k);
    hfrag b2 = *(const hfrag*)(vb + 2 * E * VSTR + m * VSTR + k);
    #pragma unroll
    for (int t = 0; t < TT; ++t) {
      const int row = (w + t * 4) * 16 + m;
      hfrag a = *(const hfrag*)(W + (size_t)row * C + k);
      acc[t][0] = mfma(a, b0, acc[t][0]);
      acc[t][1] = mfma(a, b1, acc[t][1]);
      acc[t][2] = mfma(a, b2, acc[t][2]);
    }
  }
}

// Dual scalar GEMM sharing B: accA += Wa*s (O=TTA*64), accB += Wb*s (O=TTB*64)
template<int TTA, int TTB, int KS>
__device__ __forceinline__ void gemmS2(const _Float16* __restrict__ Wa,
                                       const _Float16* __restrict__ Wb,
                                       const _Float16* sb,
                                       ffrag (&accA)[TTA], ffrag (&accB)[TTB]) {
  const int C = KS * 32;
  const int m = threadIdx.x & 15;
  const int q = (threadIdx.x >> 4) & 3;
  const int w = threadIdx.x >> 6;
  #pragma unroll
  for (int ks = 0; ks < KS; ++ks) {
    const int k = ks * 32 + q * 8;
    hfrag b = *(const hfrag*)(sb + m * SSTR + k);
    #pragma unroll
    for (int t = 0; t < TTA; ++t) {
      const int row = (w + t * 4) * 16 + m;
      hfrag a = *(const hfrag*)(Wa + (size_t)row * C + k);
      accA[t] = mfma(a, b, accA[t]);
    }
    #pragma unroll
    for (int t = 0; t < TTB; ++t) {
      const int row = (w + t * 4) * 16 + m;
      hfrag a = *(const hfrag*)(Wb + (size_t)row * C + k);
      accB[t] = mfma(a, b, accB[t]);
    }
  }
}

// Store a C/D fragment into an [e][k] LDS buffer (4 consecutive k = rows).
__device__ __forceinline__ void stCD(_Float16* buf, int stride, int tile, ffrag v) {
  const int e = threadIdx.x & 15;
  const int q = (threadIdx.x >> 4) & 3;
  h4 p;
  p[0] = (_Float16)v[0]; p[1] = (_Float16)v[1];
  p[2] = (_Float16)v[2]; p[3] = (_Float16)v[3];
  *(h4*)(buf + e * stride + tile * 16 + q * 4) = p;
}

// ---------------- generic gv layer ----------------
// TT: vector-out tiles (O_v/64); KSC: K of Wvh/Wvo_f (=C/32); KSS: K of Ws/WgWs;
// LEAKY: leaky-relu on scalar out; HASD: vn_leaky_relu on vector out.
// soff: where next layer's scalar features go inside scat.
template<int TT, int KSC, int KSS, bool LEAKY, bool HASD>
__device__ __forceinline__ void gv_layer(
    const _Float16* Wvh, const _Float16* Wvof,
    const _Float16* Ws, const _Float16* Wgs, const _Float16* Wd,
    const float* bg, _Float16* sv, _Float16* scat, int soff) {
  const int wv = threadIdx.x >> 6;
  const int q  = (threadIdx.x >> 4) & 3;
  const ffrag zero = {0.f, 0.f, 0.f, 0.f};

  // P1: vh (for vnorm) + fused out_v, both read sv
  ffrag vh[TT][3], ov[TT][3];
  #pragma unroll
  for (int i = 0; i < TT; ++i)
    for (int c = 0; c < 3; ++c) { vh[i][c] = zero; ov[i][c] = zero; }
  gemmV2<TT, KSC>(Wvh, Wvof, sv, vh, ov);
  #pragma unroll
  for (int i = 0; i < TT; ++i) {
    ffrag n;
    #pragma unroll
    for (int r = 0; r < 4; ++r)
      n[r] = sqrtf(vh[i][0][r]*vh[i][0][r] + vh[i][1][r]*vh[i][1][r] + vh[i][2][r]*vh[i][2][r]);
    stCD(scat, SSTR, wv + i * 4, n);
  }
  __syncthreads();

  // P2: out_s + fused gate-pre, both read scat
  ffrag so[2], g[TT];
  so[0] = zero; so[1] = zero;
  #pragma unroll
  for (int i = 0; i < TT; ++i) g[i] = zero;
  gemmS2<2, TT, KSS>(Ws, Wgs, scat, so, g);
  __syncthreads();

  // P3: store (leaky) scalar for next layer; gate * out_v -> sv
  #pragma unroll
  for (int i = 0; i < 2; ++i) {
    ffrag l;
    #pragma unroll
    for (int r = 0; r < 4; ++r) {
      float x = so[i][r];
      l[r] = LEAKY ? (x >= 0.f ? x : SLOPE_SCA * x) : x;
    }
    stCD(scat + soff, SSTR, wv + i * 4, l);
  }
  #pragma unroll
  for (int i = 0; i < TT; ++i) {
    const int tile = wv + i * 4;
    const float4 b = *(const float4*)(bg + tile * 16 + q * 4);
    const float bb[4] = {b.x, b.y, b.z, b.w};
    #pragma unroll
    for (int r = 0; r < 4; ++r) {
      float gg = 1.f / (1.f + expf(-(g[i][r] + bb[r])));
      ov[i][0][r] *= gg; ov[i][1][r] *= gg; ov[i][2][r] *= gg;
    }
    for (int c = 0; c < 3; ++c) stCD(sv + c * E * VSTR, VSTR, tile, ov[i][c]);
  }
  __syncthreads();

  // P4/P5: vn_leaky_relu
  if (HASD) {
    ffrag d[TT][3];
    #pragma unroll
    for (int i = 0; i < TT; ++i) for (int c = 0; c < 3; ++c) d[i][c] = zero;
    gemmV<TT, TT * 2>(Wd, sv, d);
    __syncthreads();
    #pragma unroll
    for (int i = 0; i < TT; ++i) {
      #pragma unroll
      for (int r = 0; r < 4; ++r) {
        float x0 = ov[i][0][r], x1 = ov[i][1][r], x2 = ov[i][2][r];
        float d0 = d[i][0][r],  d1 = d[i][1][r],  d2 = d[i][2][r];
        float dot = x0*d0 + x1*d1 + x2*d2;
        float kk = dot / (d0*d0 + d1*d1 + d2*d2 + EPS_VN);
        if (dot < 0.f) {
          ov[i][0][r] = SLOPE_VN*x0 + (1.f-SLOPE_VN)*(x0 - kk*d0);
          ov[i][1][r] = SLOPE_VN*x1 + (1.f-SLOPE_VN)*(x1 - kk*d1);
          ov[i][2][r] = SLOPE_VN*x2 + (1.f-SLOPE_VN)*(x2 - kk*d2);
        }
      }
      for (int c = 0; c < 3; ++c) stCD(sv + c * E * VSTR, VSTR, wv + i * 4, ov[i][c]);
    }
    __syncthreads();
  }
}

// ---------------- main kernel ----------------
struct WB {
  const _Float16 *g1_Wvh,*g1_Wvo,*g1_Ws,*g1_Wgs,*g1_Wd;
  const _Float16 *g2_Wvh,*g2_Wvo,*g2_Ws,*g2_Wgs;
  const _Float16 *a1_Wvh,*a1_Wvo,*a1_Ws,*a1_Wgs,*a1_Wd;
  const _Float16 *a2_Wvh,*a2_Wvo,*a2_Ws,*a2_Wgs,*a2_Wd;
  const _Float16 *f_Wvh;
  const float *g1_bg,*g2_bg,*a1_bg,*a2_bg,*f_Ws;
};

__global__ __launch_bounds__(TPB, 3) void pe_kernel(
    const float* __restrict__ h_sca, const float* __restrict__ h_vec,
    const float* __restrict__ pos_compose, const float* __restrict__ pos,
    WB W, const int* __restrict__ idx_focal, float* __restrict__ out, int F) {
  __shared__ __align__(16) _Float16 sv[3 * E * VSTR];   // vector features [comp][e][k]
  __shared__ __align__(16) _Float16 scat[E * SSTR];     // [vnorm | s | ...] per element
  __shared__ float srel[E * 3];

  const int t = threadIdx.x;
  const int wv = t >> 6;
  const int el = t >> 4;
  const int c0 = t & 15;
  const int eg = blockIdx.x * E + el;

  // ---- gather (f32 -> f16 LDS) ----
  {
    const int idx = (eg < F) ? idx_focal[eg] : 0;
    for (int c = c0; c < 64; c += 16) {
      const float* p = h_vec + (size_t)idx * 192 + c * 3;
      sv[0 * E * VSTR + el * VSTR + c] = (_Float16)p[0];
      sv[1 * E * VSTR + el * VSTR + c] = (_Float16)p[1];
      sv[2 * E * VSTR + el * VSTR + c] = (_Float16)p[2];
    }
    for (int c = c0; c < 256; c += 16)
      scat[el * SSTR + 128 + c] = (_Float16)h_sca[(size_t)idx * 256 + c];
    if (c0 < 3 && eg < F)
      srel[el * 3 + c0] = pos[(size_t)eg * 3 + c0] - pos_compose[(size_t)idx * 3 + c0];
  }
  __syncthreads();

  // g1: perceptron, cat=[vnorm 0:128 | s 128:384], next s -> [128:256]
  gv_layer<2, 2, 12, true, true>(W.g1_Wvh, W.g1_Wvo, W.g1_Ws, W.g1_Wgs, W.g1_Wd,
                                 W.g1_bg, sv, scat, 128);
  // g2: linear, cat=[vnorm 0:128 | s 128:256], next s -> [256:384]
  gv_layer<2, 4, 8, false, false>(W.g2_Wvh, W.g2_Wvo, W.g2_Ws, W.g2_Wgs, nullptr,
                                  W.g2_bg, sv, scat, 256);
  // a1: perceptron, cat=[vnorm 0:256 | s 256:384], next s -> [128:256]
  gv_layer<4, 4, 12, true, true>(W.a1_Wvh, W.a1_Wvo, W.a1_Ws, W.a1_Wgs, W.a1_Wd,
                                 W.a1_bg, sv, scat, 128);

  // inner[e][h] = <v1[128+h], relpos[e]> -> scat[256:384]
  {
    const float r0 = srel[el*3+0], r1 = srel[el*3+1], r2 = srel[el*3+2];
    for (int h = c0; h < 128; h += 16) {
      float x0 = (float)sv[0 * E * VSTR + el * VSTR + 128 + h];
      float x1 = (float)sv[1 * E * VSTR + el * VSTR + 128 + h];
      float x2 = (float)sv[2 * E * VSTR + el * VSTR + 128 + h];
      scat[el * SSTR + 256 + h] = (_Float16)(x0*r0 + x1*r1 + x2*r2);
    }
  }
  // (visibility guaranteed by a2's P1 barrier; a2 P1 only reads sv rows 0:128)

  // a2: perceptron, cat=[vnorm 0:128 | s1 128:256 | inner 256:384], next s -> [128:256]
  gv_layer<2, 4, 12, true, true>(W.a2_Wvh, W.a2_Wvo, W.a2_Ws, W.a2_Wgs, W.a2_Wd,
                                 W.a2_bg, sv, scat, 128);

  // f: vnorm + final dot
  {
    const ffrag zero = {0.f,0.f,0.f,0.f};
    ffrag vh[2][3];
    #pragma unroll
    for (int i = 0; i < 2; ++i) for (int c = 0; c < 3; ++c) vh[i][c] = zero;
    gemmV<2, 4>(W.f_Wvh, sv, vh);
    #pragma unroll
    for (int i = 0; i < 2; ++i) {
      ffrag n;
      for (int r = 0; r < 4; ++r)
        n[r] = sqrtf(vh[i][0][r]*vh[i][0][r] + vh[i][1][r]*vh[i][1][r] + vh[i][2][r]*vh[i][2][r]);
      stCD(scat, SSTR, wv + i * 4, n);
    }
    __syncthreads();

    float part = 0.f;
    for (int c = c0; c < 256; c += 16)
      part += (float)scat[el * SSTR + c] * W.f_Ws[c];
    part += __shfl_xor(part, 8, 16);
    part += __shfl_xor(part, 4, 16);
    part += __shfl_xor(part, 2, 16);
    part += __shfl_xor(part, 1, 16);
    if (c0 == 0 && eg < F) out[eg] = part;
  }
}

extern "C" void kernel_launch(void* const* d_in, const int* in_sizes, int n_in,
                              void* d_out, int out_size, void* d_ws, size_t ws_size,
                              hipStream_t stream) {
  const float* h_sca       = (const float*)d_in[0];
  const float* h_vec       = (const float*)d_in[1];
  const float* pos_compose = (const float*)d_in[2];
  const float* pos         = (const float*)d_in[3];
  const int* idx_focal     = (const int*)d_in[29];
  const int F = in_sizes[29];

  _Float16* wsp = (_Float16*)d_ws;
  size_t off = 0;
  auto alloc = [&](int n) { _Float16* p = wsp + off; off += (size_t)(n + 7) & ~7ull; return p; };

  // plain f16 conversions
  const int widx[12] = {4, 5, 9, 10, 11, 15, 16, 20, 21, 22, 26, 27};
  CvtJobs CJ;
  _Float16* plain[12];
  for (int j = 0; j < 12; ++j) {
    CJ.src[j] = (const float*)d_in[widx[j]];
    CJ.n[j]   = in_sizes[widx[j]];
    plain[j]  = alloc(CJ.n[j]);
    CJ.dst[j] = plain[j];
  }

  // fused products: 0-3 Wvo@Wvh, 4-7 Wg@Ws
  FuseJobs FJ;
  _Float16* fused[8];
  const int voA[4] = {6, 12, 17, 23}, voB[4] = {4, 10, 15, 21};
  const int voO[4] = {128, 128, 256, 128}, voH[4] = {128, 128, 256, 128}, voC[4] = {64, 128, 128, 128};
  const int gsA[4] = {7, 13, 18, 24}, gsB[4] = {5, 11, 16, 22};
  const int gsO[4] = {128, 128, 256, 128}, gsH[4] = {128, 128, 128, 128}, gsC[4] = {384, 256, 384, 384};
  for (int j = 0; j < 4; ++j) {
    FJ.A[j] = (const float*)d_in[voA[j]]; FJ.B[j] = (const float*)d_in[voB[j]];
    FJ.O[j] = voO[j]; FJ.H[j] = voH[j]; FJ.C[j] = voC[j];
    fused[j] = alloc(voO[j] * voC[j]); FJ.out[j] = fused[j];
  }
  for (int j = 0; j < 4; ++j) {
    FJ.A[4+j] = (const float*)d_in[gsA[j]]; FJ.B[4+j] = (const float*)d_in[gsB[j]];
    FJ.O[4+j] = gsO[j]; FJ.H[4+j] = gsH[j]; FJ.C[4+j] = gsC[j];
    fused[4+j] = alloc(gsO[j] * gsC[j]); FJ.out[4+j] = fused[4+j];
  }

  cvt_kernel<<<dim3(32, 12), dim3(256), 0, stream>>>(CJ);
  fuse_kernel<<<dim3(256, 8), dim3(128), 0, stream>>>(FJ);

  WB W;
  W.g1_Wvh = plain[0]; W.g1_Ws = plain[1]; W.g1_Wd = plain[2];
  W.g2_Wvh = plain[3]; W.g2_Ws = plain[4];
  W.a1_Wvh = plain[5]; W.a1_Ws = plain[6]; W.a1_Wd = plain[7];
  W.a2_Wvh = plain[8]; W.a2_Ws = plain[9]; W.a2_Wd = plain[10];
  W.f_Wvh  = plain[11];
  W.g1_Wvo = fused[0]; W.g2_Wvo = fused[1]; W.a1_Wvo = fused[2]; W.a2_Wvo = fused[3];
  W.g1_Wgs = fused[4]; W.g2_Wgs = fused[5]; W.a1_Wgs = fused[6]; W.a2_Wgs = fused[7];
  W.g1_bg = (const float*)d_in[8];
  W.g2_bg = (const float*)d_in[14];
  W.a1_bg = (const float*)d_in[19];
  W.a2_bg = (const float*)d_in[25];
  W.f_Ws  = (const float*)d_in[28];

  const int blocks = (F + E - 1) / E;
  pe_kernel<<<dim3(blocks), dim3(TPB), 0, stream>>>(
      h_sca, h_vec, pos_compose, pos, W, idx_focal, (float*)d_out, F);
}

// Round 4
// 1360.850 us; speedup vs baseline: 1.0091x; 1.0091x over previous
//
#include <hip/hip_runtime.h>
#include <math.h>

#define TPB 256
#define E 16           // elements per block
#define VSTR 264       // [e][k] stride for vector-activation LDS (f16)
#define SSTR 392       // scat stride
#define SLOPE_VN 0.2f
#define SLOPE_SCA 0.01f
#define EPS_VN 1e-6f

using hfrag = __attribute__((ext_vector_type(8))) _Float16;
using h4    = __attribute__((ext_vector_type(4))) _Float16;
using ffrag = __attribute__((ext_vector_type(4))) float;

__device__ __forceinline__ ffrag mfma(hfrag a, hfrag b, ffrag c) {
  return __builtin_amdgcn_mfma_f32_16x16x32_f16(a, b, c, 0, 0, 0);
}

// ---------------- pre-pass kernels ----------------
struct CvtJobs { const float* src[12]; _Float16* dst[12]; int n[12]; };

__global__ void cvt_kernel(CvtJobs J) {
  const int j = blockIdx.y;
  const float* __restrict__ s = J.src[j];
  _Float16* __restrict__ d = J.dst[j];
  const int n = J.n[j];
  for (int i = blockIdx.x * blockDim.x + threadIdx.x; i < n;
       i += gridDim.x * blockDim.x)
    d[i] = (_Float16)s[i];
}

// out[o][c] = sum_h A[o*H+h] * B[h*C+c]   (f32 in, f16 out)
struct FuseJobs { const float* A[8]; const float* B[8]; _Float16* out[8]; int O[8], H[8], C[8]; };

__global__ void fuse_kernel(FuseJobs J) {
  const int j = blockIdx.y;
  const int o = blockIdx.x;
  if (o >= J.O[j]) return;
  const float* __restrict__ A = J.A[j] + (size_t)o * J.H[j];
  const float* __restrict__ B = J.B[j];
  _Float16* __restrict__ out = J.out[j] + (size_t)o * J.C[j];
  const int H = J.H[j], C = J.C[j];
  for (int c = threadIdx.x; c < C; c += blockDim.x) {
    float acc = 0.f;
    for (int h = 0; h < H; ++h) acc += A[h] * B[(size_t)h * C + c];
    out[c] = (_Float16)acc;
  }
}

// ---------------- GEMM helpers ----------------
// Single vector GEMM: acc[t][comp] += W * v_comp   (K = KS*32)
template<int TT, int KS>
__device__ __forceinline__ void gemmV(const _Float16* __restrict__ W,
                                      const _Float16* vb, ffrag (&acc)[TT][3]) {
  const int C = KS * 32;
  const int m = threadIdx.x & 15;
  const int q = (threadIdx.x >> 4) & 3;
  const int w = threadIdx.x >> 6;
  #pragma unroll
  for (int ks = 0; ks < KS; ++ks) {
    const int k = ks * 32 + q * 8;
    hfrag b0 = *(const hfrag*)(vb + 0 * E * VSTR + m * VSTR + k);
    hfrag b1 = *(const hfrag*)(vb + 1 * E * VSTR + m * VSTR + k);
    hfrag b2 = *(const hfrag*)(vb + 2 * E * VSTR + m * VSTR + k);
    #pragma unroll
    for (int t = 0; t < TT; ++t) {
      const int row = (w + t * 4) * 16 + m;
      hfrag a = *(const hfrag*)(W + (size_t)row * C + k);
      acc[t][0] = mfma(a, b0, acc[t][0]);
      acc[t][1] = mfma(a, b1, acc[t][1]);
      acc[t][2] = mfma(a, b2, acc[t][2]);
    }
  }
}

// Dual scalar GEMM sharing B: accA += Wa*s (O=TTA*64), accB += Wb*s (O=TTB*64)
template<int TTA, int TTB, int KS>
__device__ __forceinline__ void gemmS2(const _Float16* __restrict__ Wa,
                                       const _Float16* __restrict__ Wb,
                                       const _Float16* sb,
                                       ffrag (&accA)[TTA], ffrag (&accB)[TTB]) {
  const int C = KS * 32;
  const int m = threadIdx.x & 15;
  const int q = (threadIdx.x >> 4) & 3;
  const int w = threadIdx.x >> 6;
  #pragma unroll
  for (int ks = 0; ks < KS; ++ks) {
    const int k = ks * 32 + q * 8;
    hfrag b = *(const hfrag*)(sb + m * SSTR + k);
    #pragma unroll
    for (int t = 0; t < TTA; ++t) {
      const int row = (w + t * 4) * 16 + m;
      hfrag a = *(const hfrag*)(Wa + (size_t)row * C + k);
      accA[t] = mfma(a, b, accA[t]);
    }
    #pragma unroll
    for (int t = 0; t < TTB; ++t) {
      const int row = (w + t * 4) * 16 + m;
      hfrag a = *(const hfrag*)(Wb + (size_t)row * C + k);
      accB[t] = mfma(a, b, accB[t]);
    }
  }
}

// Store a C/D fragment into an [e][k] LDS buffer (4 consecutive k = rows).
__device__ __forceinline__ void stCD(_Float16* buf, int stride, int tile, ffrag v) {
  const int e = threadIdx.x & 15;
  const int q = (threadIdx.x >> 4) & 3;
  h4 p;
  p[0] = (_Float16)v[0]; p[1] = (_Float16)v[1];
  p[2] = (_Float16)v[2]; p[3] = (_Float16)v[3];
  *(h4*)(buf + e * stride + tile * 16 + q * 4) = p;
}

// Load back 4 rows of one component from an [e][k] buffer (C/D-layout addressing).
__device__ __forceinline__ h4 ldCD(const _Float16* buf, int tile) {
  const int e = threadIdx.x & 15;
  const int q = (threadIdx.x >> 4) & 3;
  return *(const h4*)(buf + e * VSTR + tile * 16 + q * 4);
}

// ---------------- generic gv layer ----------------
// TT: vector-out tiles (O_v/64); KSC: K of Wvh/Wvo_f (=C/32); KSS: K of Ws/WgWs;
// LEAKY: leaky-relu on scalar out; HASD: vn_leaky_relu on vector out.
// soff: where next layer's scalar features go inside scat.
template<int TT, int KSC, int KSS, bool LEAKY, bool HASD>
__device__ __forceinline__ void gv_layer(
    const _Float16* Wvh, const _Float16* Wvof,
    const _Float16* Ws, const _Float16* Wgs, const _Float16* Wd,
    const float* bg, _Float16* sv, _Float16* scat, int soff) {
  const int wv = threadIdx.x >> 6;
  const int q  = (threadIdx.x >> 4) & 3;
  const ffrag zero = {0.f, 0.f, 0.f, 0.f};

  // P1: vh (only for vnorm) — vh regs die at the barrier
  {
    ffrag vh[TT][3];
    #pragma unroll
    for (int i = 0; i < TT; ++i) for (int c = 0; c < 3; ++c) vh[i][c] = zero;
    gemmV<TT, KSC>(Wvh, sv, vh);
    #pragma unroll
    for (int i = 0; i < TT; ++i) {
      ffrag n;
      #pragma unroll
      for (int r = 0; r < 4; ++r)
        n[r] = sqrtf(vh[i][0][r]*vh[i][0][r] + vh[i][1][r]*vh[i][1][r] + vh[i][2][r]*vh[i][2][r]);
      stCD(scat, SSTR, wv + i * 4, n);
    }
  }
  __syncthreads();

  // P2: out_s + fused gate-pre (read scat) and fused out_v (reads sv, unmodified)
  ffrag so[2], g[TT], ov[TT][3];
  so[0] = zero; so[1] = zero;
  #pragma unroll
  for (int i = 0; i < TT; ++i) { g[i] = zero; for (int c = 0; c < 3; ++c) ov[i][c] = zero; }
  gemmS2<2, TT, KSS>(Ws, Wgs, scat, so, g);
  gemmV<TT, KSC>(Wvof, sv, ov);
  __syncthreads();

  // P3: store (leaky) scalar for next layer; gate * out_v -> sv
  #pragma unroll
  for (int i = 0; i < 2; ++i) {
    ffrag l;
    #pragma unroll
    for (int r = 0; r < 4; ++r) {
      float x = so[i][r];
      l[r] = LEAKY ? (x >= 0.f ? x : SLOPE_SCA * x) : x;
    }
    stCD(scat + soff, SSTR, wv + i * 4, l);
  }
  #pragma unroll
  for (int i = 0; i < TT; ++i) {
    const int tile = wv + i * 4;
    const float4 b = *(const float4*)(bg + tile * 16 + q * 4);
    const float bb[4] = {b.x, b.y, b.z, b.w};
    #pragma unroll
    for (int r = 0; r < 4; ++r) {
      float gg = 1.f / (1.f + expf(-(g[i][r] + bb[r])));
      ov[i][0][r] *= gg; ov[i][1][r] *= gg; ov[i][2][r] *= gg;
    }
    for (int c = 0; c < 3; ++c) stCD(sv + c * E * VSTR, VSTR, tile, ov[i][c]);
  }
  __syncthreads();
  // ov dies here — vn-apply reloads x from sv instead of keeping 48 regs live

  // P4/P5: vn_leaky_relu
  if (HASD) {
    ffrag d[TT][3];
    #pragma unroll
    for (int i = 0; i < TT; ++i) for (int c = 0; c < 3; ++c) d[i][c] = zero;
    gemmV<TT, TT * 2>(Wd, sv, d);
    __syncthreads();
    #pragma unroll
    for (int i = 0; i < TT; ++i) {
      const int tile = wv + i * 4;
      h4 x0 = ldCD(sv + 0 * E * VSTR, tile);
      h4 x1 = ldCD(sv + 1 * E * VSTR, tile);
      h4 x2 = ldCD(sv + 2 * E * VSTR, tile);
      ffrag o0, o1, o2;
      #pragma unroll
      for (int r = 0; r < 4; ++r) {
        float a0 = (float)x0[r], a1 = (float)x1[r], a2 = (float)x2[r];
        float d0 = d[i][0][r], d1 = d[i][1][r], d2 = d[i][2][r];
        float dot = a0*d0 + a1*d1 + a2*d2;
        float kk = dot / (d0*d0 + d1*d1 + d2*d2 + EPS_VN);
        if (dot < 0.f) {
          a0 = SLOPE_VN*a0 + (1.f-SLOPE_VN)*(a0 - kk*d0);
          a1 = SLOPE_VN*a1 + (1.f-SLOPE_VN)*(a1 - kk*d1);
          a2 = SLOPE_VN*a2 + (1.f-SLOPE_VN)*(a2 - kk*d2);
        }
        o0[r] = a0; o1[r] = a1; o2[r] = a2;
      }
      stCD(sv + 0 * E * VSTR, VSTR, tile, o0);
      stCD(sv + 1 * E * VSTR, VSTR, tile, o1);
      stCD(sv + 2 * E * VSTR, VSTR, tile, o2);
    }
    __syncthreads();
  }
}

// ---------------- main kernel ----------------
struct WB {
  const _Float16 *g1_Wvh,*g1_Wvo,*g1_Ws,*g1_Wgs,*g1_Wd;
  const _Float16 *g2_Wvh,*g2_Wvo,*g2_Ws,*g2_Wgs;
  const _Float16 *a1_Wvh,*a1_Wvo,*a1_Ws,*a1_Wgs,*a1_Wd;
  const _Float16 *a2_Wvh,*a2_Wvo,*a2_Ws,*a2_Wgs,*a2_Wd;
  const _Float16 *f_Wvh;
  const float *g1_bg,*g2_bg,*a1_bg,*a2_bg,*f_Ws;
};

__global__ __launch_bounds__(TPB, 3) void pe_kernel(
    const float* __restrict__ h_sca, const float* __restrict__ h_vec,
    const float* __restrict__ pos_compose, const float* __restrict__ pos,
    WB W, const int* __restrict__ idx_focal, float* __restrict__ out, int F) {
  __shared__ __align__(16) _Float16 sv[3 * E * VSTR];   // vector features [comp][e][k]
  __shared__ __align__(16) _Float16 scat[E * SSTR];     // [vnorm | s | ...] per element
  __shared__ float srel[E * 3];

  const int t = threadIdx.x;
  const int wv = t >> 6;
  const int el = t >> 4;
  const int c0 = t & 15;
  const int eg = blockIdx.x * E + el;

  // ---- gather (f32 -> f16 LDS) ----
  {
    const int idx = (eg < F) ? idx_focal[eg] : 0;
    for (int c = c0; c < 64; c += 16) {
      const float* p = h_vec + (size_t)idx * 192 + c * 3;
      sv[0 * E * VSTR + el * VSTR + c] = (_Float16)p[0];
      sv[1 * E * VSTR + el * VSTR + c] = (_Float16)p[1];
      sv[2 * E * VSTR + el * VSTR + c] = (_Float16)p[2];
    }
    for (int c = c0; c < 256; c += 16)
      scat[el * SSTR + 128 + c] = (_Float16)h_sca[(size_t)idx * 256 + c];
    if (c0 < 3 && eg < F)
      srel[el * 3 + c0] = pos[(size_t)eg * 3 + c0] - pos_compose[(size_t)idx * 3 + c0];
  }
  __syncthreads();

  // g1: perceptron, cat=[vnorm 0:128 | s 128:384], next s -> [128:256]
  gv_layer<2, 2, 12, true, true>(W.g1_Wvh, W.g1_Wvo, W.g1_Ws, W.g1_Wgs, W.g1_Wd,
                                 W.g1_bg, sv, scat, 128);
  // g2: linear, cat=[vnorm 0:128 | s 128:256], next s -> [256:384]
  gv_layer<2, 4, 8, false, false>(W.g2_Wvh, W.g2_Wvo, W.g2_Ws, W.g2_Wgs, nullptr,
                                  W.g2_bg, sv, scat, 256);
  // a1: perceptron, cat=[vnorm 0:256 | s 256:384], next s -> [128:256]
  gv_layer<4, 4, 12, true, true>(W.a1_Wvh, W.a1_Wvo, W.a1_Ws, W.a1_Wgs, W.a1_Wd,
                                 W.a1_bg, sv, scat, 128);

  // inner[e][h] = <v1[128+h], relpos[e]> -> scat[256:384]
  {
    const float r0 = srel[el*3+0], r1 = srel[el*3+1], r2 = srel[el*3+2];
    for (int h = c0; h < 128; h += 16) {
      float x0 = (float)sv[0 * E * VSTR + el * VSTR + 128 + h];
      float x1 = (float)sv[1 * E * VSTR + el * VSTR + 128 + h];
      float x2 = (float)sv[2 * E * VSTR + el * VSTR + 128 + h];
      scat[el * SSTR + 256 + h] = (_Float16)(x0*r0 + x1*r1 + x2*r2);
    }
  }
  // (visibility guaranteed by a2's P1 barrier; a2 P1 only touches sv + scat[0:128])

  // a2: perceptron, cat=[vnorm 0:128 | s1 128:256 | inner 256:384], next s -> [128:256]
  gv_layer<2, 4, 12, true, true>(W.a2_Wvh, W.a2_Wvo, W.a2_Ws, W.a2_Wgs, W.a2_Wd,
                                 W.a2_bg, sv, scat, 128);

  // f: vnorm + final dot
  {
    const ffrag zero = {0.f,0.f,0.f,0.f};
    ffrag vh[2][3];
    #pragma unroll
    for (int i = 0; i < 2; ++i) for (int c = 0; c < 3; ++c) vh[i][c] = zero;
    gemmV<2, 4>(W.f_Wvh, sv, vh);
    #pragma unroll
    for (int i = 0; i < 2; ++i) {
      ffrag n;
      for (int r = 0; r < 4; ++r)
        n[r] = sqrtf(vh[i][0][r]*vh[i][0][r] + vh[i][1][r]*vh[i][1][r] + vh[i][2][r]*vh[i][2][r]);
      stCD(scat, SSTR, wv + i * 4, n);
    }
    __syncthreads();

    float part = 0.f;
    for (int c = c0; c < 256; c += 16)
      part += (float)scat[el * SSTR + c] * W.f_Ws[c];
    part += __shfl_xor(part, 8, 16);
    part += __shfl_xor(part, 4, 16);
    part += __shfl_xor(part, 2, 16);
    part += __shfl_xor(part, 1, 16);
    if (c0 == 0 && eg < F) out[eg] = part;
  }
}

extern "C" void kernel_launch(void* const* d_in, const int* in_sizes, int n_in,
                              void* d_out, int out_size, void* d_ws, size_t ws_size,
                              hipStream_t stream) {
  const float* h_sca       = (const float*)d_in[0];
  const float* h_vec       = (const float*)d_in[1];
  const float* pos_compose = (const float*)d_in[2];
  const float* pos         = (const float*)d_in[3];
  const int* idx_focal     = (const int*)d_in[29];
  const int F = in_sizes[29];

  _Float16* wsp = (_Float16*)d_ws;
  size_t off = 0;
  auto alloc = [&](int n) { _Float16* p = wsp + off; off += (size_t)(n + 7) & ~7ull; return p; };

  // plain f16 conversions
  const int widx[12] = {4, 5, 9, 10, 11, 15, 16, 20, 21, 22, 26, 27};
  CvtJobs CJ;
  _Float16* plain[12];
  for (int j = 0; j < 12; ++j) {
    CJ.src[j] = (const float*)d_in[widx[j]];
    CJ.n[j]   = in_sizes[widx[j]];
    plain[j]  = alloc(CJ.n[j]);
    CJ.dst[j] = plain[j];
  }

  // fused products: 0-3 Wvo@Wvh, 4-7 Wg@Ws
  FuseJobs FJ;
  _Float16* fused[8];
  const int voA[4] = {6, 12, 17, 23}, voB[4] = {4, 10, 15, 21};
  const int voO[4] = {128, 128, 256, 128}, voH[4] = {128, 128, 256, 128}, voC[4] = {64, 128, 128, 128};
  const int gsA[4] = {7, 13, 18, 24}, gsB[4] = {5, 11, 16, 22};
  const int gsO[4] = {128, 128, 256, 128}, gsH[4] = {128, 128, 128, 128}, gsC[4] = {384, 256, 384, 384};
  for (int j = 0; j < 4; ++j) {
    FJ.A[j] = (const float*)d_in[voA[j]]; FJ.B[j] = (const float*)d_in[voB[j]];
    FJ.O[j] = voO[j]; FJ.H[j] = voH[j]; FJ.C[j] = voC[j];
    fused[j] = alloc(voO[j] * voC[j]); FJ.out[j] = fused[j];
  }
  for (int j = 0; j < 4; ++j) {
    FJ.A[4+j] = (const float*)d_in[gsA[j]]; FJ.B[4+j] = (const float*)d_in[gsB[j]];
    FJ.O[4+j] = gsO[j]; FJ.H[4+j] = gsH[j]; FJ.C[4+j] = gsC[j];
    fused[4+j] = alloc(gsO[j] * gsC[j]); FJ.out[4+j] = fused[4+j];
  }

  cvt_kernel<<<dim3(32, 12), dim3(256), 0, stream>>>(CJ);
  fuse_kernel<<<dim3(256, 8), dim3(128), 0, stream>>>(FJ);

  WB W;
  W.g1_Wvh = plain[0]; W.g1_Ws = plain[1]; W.g1_Wd = plain[2];
  W.g2_Wvh = plain[3]; W.g2_Ws = plain[4];
  W.a1_Wvh = plain[5]; W.a1_Ws = plain[6]; W.a1_Wd = plain[7];
  W.a2_Wvh = plain[8]; W.a2_Ws = plain[9]; W.a2_Wd = plain[10];
  W.f_Wvh  = plain[11];
  W.g1_Wvo = fused[0]; W.g2_Wvo = fused[1]; W.a1_Wvo = fused[2]; W.a2_Wvo = fused[3];
  W.g1_Wgs = fused[4]; W.g2_Wgs = fused[5]; W.a1_Wgs = fused[6]; W.a2_Wgs = fused[7];
  W.g1_bg = (const float*)d_in[8];
  W.g2_bg = (const float*)d_in[14];
  W.a1_bg = (const float*)d_in[19];
  W.a2_bg = (const float*)d_in[25];
  W.f_Ws  = (const float*)d_in[28];

  const int blocks = (F + E - 1) / E;
  pe_kernel<<<dim3(blocks), dim3(TPB), 0, stream>>>(
      h_sca, h_vec, pos_compose, pos, W, idx_focal, (float*)d_out, F);
}